// Round 17
// baseline (87.680 us; speedup 1.0000x reference)
//
#include <hip/hip_runtime.h>

#define IN_CH 96
#define OUT_CH 384
#define THREADS 384
#define TILE 32    // rows staged per buffer (12 KB each, 24 KB double-buffered)

typedef float f32x4 __attribute__((ext_vector_type(4)));
typedef float f32x2 __attribute__((ext_vector_type(2)));

// R17: R13 (85.1us) + double-buffered LDS + async-stage split (T14).
// R13 paid 2 barriers/tile; each barrier's implicit s_waitcnt vmcnt(0)
// drains the nt-store queue, and the staging loads' HBM latency was exposed
// between the two barriers. Here: ONE barrier per tile (write buf[cur],
// sync, compute buf[cur] while next tile's global loads are in flight into
// registers; they get ds_written after the NEXT barrier). Writes to
// buf[cur^1] at iter i+1 are safe: barrier(i) guarantees iter i-1's readers
// of that buffer are done. Loads are issued BEFORE the compute stores, so
// the ds_write's vmcnt wait retires only loads, never drains the stores.
__global__ __launch_bounds__(THREADS, 5) void skel_linear_kernel(
    const float* __restrict__ x,
    const float* __restrict__ weight,
    const float* __restrict__ mask,
    const float* __restrict__ bias,
    float* __restrict__ out,
    int batch)
{
    const int t     = threadIdx.x;
    const int p     = t % 192;         // channel-pair index 0..191
    const int rl    = t / 192;         // 0..1 (uniform per wave)
    const int chan  = p * 2;
    const int joint = p >> 3;
    const int jc    = (joint - 1 < 0) ? 0 : ((joint - 1 > 21) ? 21 : joint - 1);
    const int c0    = jc * 4;          // contiguous 12-col window [c0, c0+12)

    // Masked weights + bias (26 floats: proven register-resident at this size).
    float w[2][12];
    float b[2];
#pragma unroll
    for (int j = 0; j < 2; ++j) {
        const size_t row = (size_t)(chan + j) * IN_CH;
#pragma unroll
        for (int c = 0; c < 12; ++c)
            w[j][c] = weight[row + c0 + c] * mask[row + c0 + c];
        b[j] = bias[chan + j];
    }
#pragma unroll
    for (int j = 0; j < 2; ++j) {
#pragma unroll
        for (int c = 0; c < 12; ++c)
            asm volatile("" : "+v"(w[j][c]));
        asm volatile("" : "+v"(b[j]));
    }

    __shared__ float xs[2][TILE * IN_CH];   // 2 x 12 KB

    const int ntiles = batch / TILE;        // 8192
    const int stride = gridDim.x;

    // Prologue: load tile blockIdx.x into registers.
    int tile = blockIdx.x;
    {
        const f32x4* src = reinterpret_cast<const f32x4*>(
            x + (size_t)tile * (TILE * IN_CH));
        // fallthrough into loop with va/vb live
    }
    const f32x4* src0 = reinterpret_cast<const f32x4*>(
        x + (size_t)tile * (TILE * IN_CH));
    f32x4 va = src0[t];
    f32x4 vb = src0[t + THREADS];

    int cur = 0;
    while (tile < ntiles) {
        // Stage the register-held tile into buf[cur].
        *reinterpret_cast<f32x4*>(&xs[cur][4 * t])             = va;
        *reinterpret_cast<f32x4*>(&xs[cur][4 * (t + THREADS)]) = vb;
        __syncthreads();                 // staged + prior readers of buf[cur^1] done

        // Prefetch next tile (clamped, uniform) BEFORE compute/stores.
        const int tn = tile + stride;
        const int tc = (tn < ntiles) ? tn : tile;
        const f32x4* nsrc = reinterpret_cast<const f32x4*>(
            x + (size_t)tc * (TILE * IN_CH));
        va = nsrc[t];
        vb = nsrc[t + THREADS];

        // Compute tile from buf[cur] (16 rows/thread), nt stores.
        float* outb = out + (size_t)tile * (TILE * OUT_CH) + chan;
#pragma unroll 4
        for (int k = 0; k < TILE / 2; ++k) {
            const int rloc = 2 * k + rl;
            const float* xr = &xs[cur][rloc * IN_CH + c0];
            const f32x4 xa = *reinterpret_cast<const f32x4*>(xr);
            const f32x4 xb2 = *reinterpret_cast<const f32x4*>(xr + 4);
            const f32x4 xc = *reinterpret_cast<const f32x4*>(xr + 8);

            f32x2 o2;
#pragma unroll
            for (int j = 0; j < 2; ++j) {
                float acc = b[j];
                acc = fmaf(w[j][0],  xa.x,  acc);
                acc = fmaf(w[j][1],  xa.y,  acc);
                acc = fmaf(w[j][2],  xa.z,  acc);
                acc = fmaf(w[j][3],  xa.w,  acc);
                acc = fmaf(w[j][4],  xb2.x, acc);
                acc = fmaf(w[j][5],  xb2.y, acc);
                acc = fmaf(w[j][6],  xb2.z, acc);
                acc = fmaf(w[j][7],  xb2.w, acc);
                acc = fmaf(w[j][8],  xc.x,  acc);
                acc = fmaf(w[j][9],  xc.y,  acc);
                acc = fmaf(w[j][10], xc.z,  acc);
                acc = fmaf(w[j][11], xc.w,  acc);
                o2[j] = acc;
            }

            __builtin_nontemporal_store(o2,
                reinterpret_cast<f32x2*>(outb + (size_t)rloc * OUT_CH));
        }

        cur ^= 1;
        tile = tn;
    }
}

extern "C" void kernel_launch(void* const* d_in, const int* in_sizes, int n_in,
                              void* d_out, int out_size, void* d_ws, size_t ws_size,
                              hipStream_t stream) {
    const float* x      = (const float*)d_in[0];
    const float* weight = (const float*)d_in[1];
    const float* mask   = (const float*)d_in[2];
    const float* bias   = (const float*)d_in[3];
    float* out          = (float*)d_out;

    const int batch = in_sizes[0] / IN_CH;   // 262144
    // 8192 tiles / 1024 blocks = exactly 8 tiles/block, 4 blocks/CU,
    // 24 waves/CU, 96 KB LDS/CU — no tail imbalance.
    const int grid = 1024;

    skel_linear_kernel<<<grid, THREADS, 0, stream>>>(x, weight, mask, bias, out, batch);
}

// Round 18
// 86.573 us; speedup vs baseline: 1.0128x; 1.0128x over previous
//
#include <hip/hip_runtime.h>

#define IN_CH 96
#define OUT_CH 384
#define THREADS 384
#define TILE 64    // rows staged per block-iteration (24 KB LDS)

typedef float f32x4 __attribute__((ext_vector_type(4)));
typedef float f32x2 __attribute__((ext_vector_type(2)));

// R18 = R13 champion (85.1us) with ONE knob: TILE 32 -> 64.
// R13's residual vs the 6.3 TB/s copy ceiling (~6%) = per-tile exposed
// staging-load latency + 2 barriers, 16x per block. R17's double-buffer
// attack regressed (register/LDS pressure); halving the number of
// exposures (4 tiles/block instead of 8) attacks the same residual with
// no new live state. Everything else proven: nt stores (2x win), pinned
// 26-float weight stash (spills at 52), ds_read_b128 broadcast from LDS
// (L1-path decongestion, +26%), grid 1024 = 4 blocks/CU uniform.
__global__ __launch_bounds__(THREADS, 5) void skel_linear_kernel(
    const float* __restrict__ x,
    const float* __restrict__ weight,
    const float* __restrict__ mask,
    const float* __restrict__ bias,
    float* __restrict__ out,
    int batch)
{
    const int t     = threadIdx.x;
    const int p     = t % 192;         // channel-pair index 0..191
    const int rl    = t / 192;         // 0..1 (uniform per wave)
    const int chan  = p * 2;
    const int joint = p >> 3;
    const int jc    = (joint - 1 < 0) ? 0 : ((joint - 1 > 21) ? 21 : joint - 1);
    const int c0    = jc * 4;          // contiguous 12-col window [c0, c0+12)

    // Masked weights + bias (26 floats: proven register-resident at this size).
    float w[2][12];
    float b[2];
#pragma unroll
    for (int j = 0; j < 2; ++j) {
        const size_t row = (size_t)(chan + j) * IN_CH;
#pragma unroll
        for (int c = 0; c < 12; ++c)
            w[j][c] = weight[row + c0 + c] * mask[row + c0 + c];
        b[j] = bias[chan + j];
    }
#pragma unroll
    for (int j = 0; j < 2; ++j) {
#pragma unroll
        for (int c = 0; c < 12; ++c)
            asm volatile("" : "+v"(w[j][c]));
        asm volatile("" : "+v"(b[j]));
    }

    __shared__ float xs[TILE * IN_CH];   // 64*96*4 = 24 KB

    const int ntiles = batch / TILE;     // 4096
    for (int tile = blockIdx.x; tile < ntiles; tile += gridDim.x) {
        // Stage 64 rows: 1536 dwordx4, 4 per thread, perfectly coalesced.
        const f32x4* src = reinterpret_cast<const f32x4*>(
            x + (size_t)tile * (TILE * IN_CH));
        __syncthreads();                 // previous tile's readers done
#pragma unroll
        for (int u = 0; u < 4; ++u)
            *reinterpret_cast<f32x4*>(&xs[4 * (t + u * THREADS)]) = src[t + u * THREADS];
        __syncthreads();                 // tile staged

        float* outb = out + (size_t)tile * (TILE * OUT_CH) + chan;
#pragma unroll 4
        for (int k = 0; k < TILE / 2; ++k) {
            const int rloc = 2 * k + rl;
            const float* xr = &xs[rloc * IN_CH + c0];
            const f32x4 xa = *reinterpret_cast<const f32x4*>(xr);
            const f32x4 xb = *reinterpret_cast<const f32x4*>(xr + 4);
            const f32x4 xc = *reinterpret_cast<const f32x4*>(xr + 8);

            f32x2 o2;
#pragma unroll
            for (int j = 0; j < 2; ++j) {
                float acc = b[j];
                acc = fmaf(w[j][0],  xa.x, acc);
                acc = fmaf(w[j][1],  xa.y, acc);
                acc = fmaf(w[j][2],  xa.z, acc);
                acc = fmaf(w[j][3],  xa.w, acc);
                acc = fmaf(w[j][4],  xb.x, acc);
                acc = fmaf(w[j][5],  xb.y, acc);
                acc = fmaf(w[j][6],  xb.z, acc);
                acc = fmaf(w[j][7],  xb.w, acc);
                acc = fmaf(w[j][8],  xc.x, acc);
                acc = fmaf(w[j][9],  xc.y, acc);
                acc = fmaf(w[j][10], xc.z, acc);
                acc = fmaf(w[j][11], xc.w, acc);
                o2[j] = acc;
            }

            __builtin_nontemporal_store(o2,
                reinterpret_cast<f32x2*>(outb + (size_t)rloc * OUT_CH));
        }
    }
}

extern "C" void kernel_launch(void* const* d_in, const int* in_sizes, int n_in,
                              void* d_out, int out_size, void* d_ws, size_t ws_size,
                              hipStream_t stream) {
    const float* x      = (const float*)d_in[0];
    const float* weight = (const float*)d_in[1];
    const float* mask   = (const float*)d_in[2];
    const float* bias   = (const float*)d_in[3];
    float* out          = (float*)d_out;

    const int batch = in_sizes[0] / IN_CH;   // 262144
    // 4096 tiles / 1024 blocks = exactly 4 tiles/block, 4 blocks/CU,
    // 24 waves/CU, 96 KB LDS/CU — no tail imbalance.
    const int grid = 1024;

    skel_linear_kernel<<<grid, THREADS, 0, stream>>>(x, weight, mask, bias, out, batch);
}